// Round 4
// baseline (16074.435 us; speedup 1.0000x reference)
//
#include <hip/hip_runtime.h>

// 6-layer GRU, T=512, B=256, I=128, H=256. ALL I/O IS FLOAT32. MFMA operands
// cvt f32->bf16 on the fly; h carried in f32; internal gx ws is bf16.
// d_out = [cur 512*256*256][finals 6*256*256] f32.
//
// R4: gru_scan rebuilt as 256-thr/4-wave (1 wave/SIMD, 512-VGPR cap) so the
// resident W_hh fragments (384 VGPRs) actually STAY resident (R3: VGPR=128 ->
// full spill of bw -> 579us/dispatch). gx now staged via global_load_lds into
// a double-buffered LDS slab (saves 24 prefetch VGPRs).

#define NLAY 6

typedef __bf16 bf16x8 __attribute__((ext_vector_type(8)));
typedef float  f32x4  __attribute__((ext_vector_type(4)));

typedef const unsigned int __attribute__((address_space(1)))* gp1_t;
typedef unsigned int __attribute__((address_space(3)))* lp3_t;

__device__ __forceinline__ float b2f(unsigned short u) {
  union { unsigned int i; float f; } v; v.i = ((unsigned int)u) << 16; return v.f;
}
__device__ __forceinline__ unsigned short f2bs(float f) {
  union { __bf16 b; unsigned short s; } v; v.b = (__bf16)f; return v.s;
}
__device__ __forceinline__ bf16x8 cvt8(f32x4 lo, f32x4 hi) {
  bf16x8 r;
#pragma unroll
  for (int i = 0; i < 4; ++i) { r[i] = (__bf16)lo[i]; r[4 + i] = (__bf16)hi[i]; }
  return r;
}

// ---------------------------------------------------------------------------
// gx[m,g] = sum_k X[m,k]*W[g,k] + bias(g);  m = t*256+b (chunk-local t)
// X: [M][K] f32, W: [768][K] f32, K in {128,256}.
// GX (bf16): (t,b,g) -> GX[((t*16 + (b>>4))*768 + g)*16 + (b&15)]
// grid = (M/128, 6), block = 256.  (unchanged from R3 - passed, ~27us)
// ---------------------------------------------------------------------------
__global__ __launch_bounds__(256) void gx_gemm(
    const float* __restrict__ X,
    const float* __restrict__ W,
    const float* __restrict__ bih,
    const float* __restrict__ bhh,
    unsigned short* __restrict__ GX,
    int K)
{
  __shared__ __align__(16) float Asf[128 * 32];
  __shared__ __align__(16) float Bsf[128 * 32];
  const int tid  = threadIdx.x;
  const int lane = tid & 63;
  const int w    = tid >> 6;
  const int wy   = w >> 1, wx = w & 1;
  const int l15  = lane & 15, q = lane >> 4;
  const int m0   = blockIdx.x * 128;
  const int n0   = blockIdx.y * 128;

  f32x4 acc[4][4];
#pragma unroll
  for (int a = 0; a < 4; ++a)
#pragma unroll
    for (int b = 0; b < 4; ++b) acc[a][b] = f32x4{0.f, 0.f, 0.f, 0.f};

  const int kiters = K >> 5;
  for (int kt = 0; kt < kiters; ++kt) {
#pragma unroll
    for (int i = 0; i < 4; ++i) {
      int ci  = (w * 4 + i) * 64 + lane;   // 0..1023 16B-chunks
      int row = ci >> 3;
      int g   = ci & 7;
      int kg  = g ^ (row & 7);
      const float* srcA = X + (size_t)(m0 + row) * K + kt * 32 + kg * 4;
      const float* srcB = W + (size_t)(n0 + row) * K + kt * 32 + kg * 4;
      __builtin_amdgcn_global_load_lds((gp1_t)(const void*)srcA,
          (lp3_t)(void*)((char*)Asf + (w * 4 + i) * 1024), 16, 0, 0);
      __builtin_amdgcn_global_load_lds((gp1_t)(const void*)srcB,
          (lp3_t)(void*)((char*)Bsf + (w * 4 + i) * 1024), 16, 0, 0);
    }
    __syncthreads();

    bf16x8 a[4], b[4];
#pragma unroll
    for (int tm = 0; tm < 4; ++tm) {
      int row = wy * 64 + tm * 16 + l15;
      int p0  = (2 * q) ^ (row & 7);
      int p1  = (2 * q + 1) ^ (row & 7);
      f32x4 lo = *(const f32x4*)(Asf + row * 32 + p0 * 4);
      f32x4 hi = *(const f32x4*)(Asf + row * 32 + p1 * 4);
      a[tm] = cvt8(lo, hi);
    }
#pragma unroll
    for (int tn = 0; tn < 4; ++tn) {
      int row = wx * 64 + tn * 16 + l15;
      int p0  = (2 * q) ^ (row & 7);
      int p1  = (2 * q + 1) ^ (row & 7);
      f32x4 lo = *(const f32x4*)(Bsf + row * 32 + p0 * 4);
      f32x4 hi = *(const f32x4*)(Bsf + row * 32 + p1 * 4);
      b[tn] = cvt8(lo, hi);
    }
#pragma unroll
    for (int tm = 0; tm < 4; ++tm)
#pragma unroll
      for (int tn = 0; tn < 4; ++tn)
        acc[tm][tn] = __builtin_amdgcn_mfma_f32_16x16x32_bf16(a[tm], b[tn], acc[tm][tn], 0, 0, 0);
    __syncthreads();
  }

#pragma unroll
  for (int tn = 0; tn < 4; ++tn) {
    int g = n0 + wx * 64 + tn * 16 + l15;
    float bias = bih[g] + (g < 512 ? bhh[g] : 0.f);
#pragma unroll
    for (int tm = 0; tm < 4; ++tm) {
#pragma unroll
      for (int r = 0; r < 4; ++r) {
        int m = m0 + wy * 64 + tm * 16 + q * 4 + r;
        int t = m >> 8, bb = m & 255;
        size_t dst = ((size_t)(t * 16 + (bb >> 4)) * 768 + g) * 16 + (bb & 15);
        GX[dst] = f2bs(acc[tm][tn][r] + bias);
      }
    }
  }
}

// ---------------------------------------------------------------------------
// Recurrent scan. 16 WGs x 256 thr (4 waves, 1 wave/SIMD -> 512 VGPR cap).
// WG owns 16 batch rows. Wave w owns gh cols [64w,64w+64) per gate:
// 12 MFMA n-tiles, W_hh bf16 B-frags resident in VGPRs (12x8 frags = 384 regs).
// h f32 in regs; bf16 h in dbuf swizzled LDS (A-op). gx staged per step into
// dbuf LDS slab via global_load_lds. 1 barrier/step.
// ---------------------------------------------------------------------------
__global__ __launch_bounds__(256, 1) void gru_scan(
    const unsigned short* __restrict__ GX,    // [Tc][16][768][16] bf16
    const float* __restrict__ Whh,            // [768][256] f32 layer base
    const float* __restrict__ bhh,            // [768] f32 (n-part used)
    float* __restrict__ hcar,                 // [256][256] f32 carry
    const float* __restrict__ h0,             // [256][256] f32 layer slice
    float* __restrict__ Y,                    // chunk out [Tc][256][256] f32
    float* __restrict__ FIN,                  // finals slice f32 or nullptr
    int Tc, int first)
{
  __shared__ __align__(16) unsigned short gxls[2][768 * 16];  // 2x24KB linear
  __shared__ __align__(16) unsigned short hbuf[2][16 * 256];  // 2x8KB swizzled
  const int wg   = blockIdx.x;
  const int b0   = wg << 4;
  const int tid  = threadIdx.x;
  const int lane = tid & 63;
  const int w    = tid >> 6;     // 0..3
  const int m    = lane & 15;
  const int q    = lane >> 4;
  const int jb   = (w << 6) + m; // col base within a gate; c adds 16

  // resident W_hh B-fragments: B[k][n], n = gate*256 + jb + 16c, k = kt*32+8q+i
  bf16x8 bw[12][8];
#pragma unroll
  for (int gate = 0; gate < 3; ++gate)
#pragma unroll
    for (int c = 0; c < 4; ++c) {
      int n = gate * 256 + jb + c * 16;
#pragma unroll
      for (int kt = 0; kt < 8; ++kt) {
        f32x4 lo = *(const f32x4*)(Whh + (size_t)n * 256 + kt * 32 + q * 8);
        f32x4 hi = *(const f32x4*)(Whh + (size_t)n * 256 + kt * 32 + q * 8 + 4);
        bw[gate * 4 + c][kt] = cvt8(lo, hi);
      }
    }

  float bhn[4];
#pragma unroll
  for (int c = 0; c < 4; ++c) bhn[c] = bhh[512 + jb + c * 16];

  // h regs: row b0+4q+r, col jb+16c
  float h[4][4];
#pragma unroll
  for (int c = 0; c < 4; ++c)
#pragma unroll
    for (int r = 0; r < 4; ++r) {
      int bb = b0 + q * 4 + r;
      int j  = jb + c * 16;
      h[c][r] = first ? h0[bb * 256 + j] : hcar[bb * 256 + j];
    }

  // init h LDS buf 0 (swizzle: ad = b*256 + (((j>>3)^(b&7))<<3) + (j&7))
#pragma unroll
  for (int c = 0; c < 4; ++c)
#pragma unroll
    for (int r = 0; r < 4; ++r) {
      int bb = q * 4 + r;
      int j  = jb + c * 16;
      int ad = bb * 256 + ((((j >> 3) ^ (bb & 7))) << 3) + (j & 7);
      hbuf[0][ad] = f2bs(h[c][r]);
    }

  // stage gx(t=0) into slab 0: 24KB = 1536 16B-chunks, 6 per thread
  {
    const unsigned short* gs = GX + (size_t)wg * 12288;
#pragma unroll
    for (int i = 0; i < 6; ++i) {
      int ch = (i * 4 + w) * 64 + lane;
      __builtin_amdgcn_global_load_lds((gp1_t)(const void*)(gs + ch * 8),
          (lp3_t)(void*)((char*)gxls[0] + (i * 4 + w) * 1024), 16, 0, 0);
    }
  }
  __syncthreads();

  float* yp = Y + (size_t)(b0 + q * 4) * 256 + jb;

  for (int t = 0; t < Tc; ++t) {
    // ---- stage gx(t+1) into other slab (lands during this step) ----
    if (t + 1 < Tc) {
      const unsigned short* gs = GX + (size_t)((t + 1) * 16 + wg) * 12288;
      unsigned short* dst = gxls[(t + 1) & 1];
#pragma unroll
      for (int i = 0; i < 6; ++i) {
        int ch = (i * 4 + w) * 64 + lane;
        __builtin_amdgcn_global_load_lds((gp1_t)(const void*)(gs + ch * 8),
            (lp3_t)(void*)((char*)dst + (i * 4 + w) * 1024), 16, 0, 0);
      }
    }

    // ---- gh = bf16(h) @ W_hh^T  (A from LDS, B resident in VGPRs) ----
    f32x4 acc[12];
#pragma unroll
    for (int i = 0; i < 12; ++i) acc[i] = f32x4{0.f, 0.f, 0.f, 0.f};
    const unsigned short* hb = hbuf[t & 1];
#pragma unroll
    for (int kt = 0; kt < 8; ++kt) {
      int ad = m * 256 + (((kt * 4 + q) ^ (m & 7)) << 3);
      bf16x8 af = *(const bf16x8*)(hb + ad);
#pragma unroll
      for (int i = 0; i < 12; ++i)
        acc[i] = __builtin_amdgcn_mfma_f32_16x16x32_bf16(af, bw[i][kt], acc[i], 0, 0, 0);
    }

    // ---- pointwise GRU cell (f32); gx from LDS slab; h' -> other h buf ----
    unsigned short* hw = hbuf[(t + 1) & 1];
    const unsigned short* gxb = gxls[t & 1];
#pragma unroll
    for (int c = 0; c < 4; ++c) {
      int g = jb + c * 16;                       // col within gate
      ushort4 ir4 = *(const ushort4*)(gxb + (g)        * 16 + q * 4);
      ushort4 iz4 = *(const ushort4*)(gxb + (g + 256)  * 16 + q * 4);
      ushort4 in4 = *(const ushort4*)(gxb + (g + 512)  * 16 + q * 4);
      const unsigned short* irp = (const unsigned short*)&ir4;
      const unsigned short* izp = (const unsigned short*)&iz4;
      const unsigned short* inp = (const unsigned short*)&in4;
#pragma unroll
      for (int r = 0; r < 4; ++r) {
        float ir  = b2f(irp[r]);
        float iz  = b2f(izp[r]);
        float inn = b2f(inp[r]);
        float rr = __builtin_amdgcn_rcpf(1.f + __expf(-(ir + acc[c][r])));
        float zz = __builtin_amdgcn_rcpf(1.f + __expf(-(iz + acc[4 + c][r])));
        float nx = inn + rr * (acc[8 + c][r] + bhn[c]);
        float nn = 1.f - 2.f * __builtin_amdgcn_rcpf(__expf(2.f * nx) + 1.f); // tanh
        float hv = nn + zz * (h[c][r] - nn);    // (1-z)*n + z*h
        h[c][r] = hv;
        int bb = q * 4 + r;
        int j  = jb + c * 16;
        int ad = bb * 256 + ((((j >> 3) ^ (bb & 7))) << 3) + (j & 7);
        hw[ad] = f2bs(hv);
        yp[r * 256 + c * 16] = hv;
      }
    }
    yp += 65536;
    __syncthreads();   // h' visible + gx(t+1) staging drained
  }

  // carry out (f32) or finals (f32)
#pragma unroll
  for (int c = 0; c < 4; ++c)
#pragma unroll
    for (int r = 0; r < 4; ++r) {
      int bb = b0 + q * 4 + r;
      int j  = jb + c * 16;
      if (FIN) FIN[bb * 256 + j] = h[c][r];
      else     hcar[bb * 256 + j] = h[c][r];
    }
}

// ---------------------------------------------------------------------------
extern "C" void kernel_launch(void* const* d_in, const int* in_sizes, int n_in,
                              void* d_out, int out_size, void* d_ws, size_t ws_size,
                              hipStream_t stream) {
  const float* x    = (const float*)d_in[0]; // [512][256][128]
  const float* h0   = (const float*)d_in[1]; // [6][256][256]
  const float* Wih0 = (const float*)d_in[2]; // [768][128]
  const float* Wih  = (const float*)d_in[3]; // [5][768][256]
  const float* Whh  = (const float*)d_in[4]; // [6][768][256]
  const float* bih  = (const float*)d_in[5]; // [6][768]
  const float* bhh  = (const float*)d_in[6]; // [6][768]
  float* out = (float*)d_out;

  // largest Tc whose ws fits: gx = Tc*16*768*16*2 B (bf16), + hcar 256KB f32
  int Tc = 128;
  while (Tc > 8) {
    size_t need = (size_t)Tc * 16 * 768 * 16 * 2 + 262144;
    if (need <= ws_size) break;
    Tc >>= 1;
  }
  const int nch = 512 / Tc;
  const size_t gxBytes = (size_t)Tc * 16 * 768 * 16 * 2;

  char* ws = (char*)d_ws;
  unsigned short* gx   = (unsigned short*)ws;
  float*          hcar = (float*)(ws + gxBytes);

  float* cur = out;                              // [512][256][256] f32
  float* fin = out + (size_t)512 * 256 * 256;    // [6][256][256] f32

  for (int l = 0; l < NLAY; ++l) {
    int K = (l == 0) ? 128 : 256;
    const float* Xl = (l == 0) ? x : cur;        // in-place chaining
    const float* Wihl = (l == 0) ? Wih0 : (Wih + (size_t)(l - 1) * 768 * 256);
    const float* Whhl = Whh + (size_t)l * 768 * 256;
    const float* bihl = bih + l * 768;
    const float* bhhl = bhh + l * 768;
    const float* h0l  = h0 + (size_t)l * 65536;

    for (int c = 0; c < nch; ++c) {
      const float* Xc = Xl + (size_t)c * Tc * 256 * K;
      gx_gemm<<<dim3(Tc * 2, 6), 256, 0, stream>>>(Xc, Wihl, bihl, bhhl, gx, K);
      gru_scan<<<dim3(16), dim3(256), 0, stream>>>(
          gx, Whhl, bhhl, hcar, h0l,
          cur + (size_t)c * Tc * 65536,
          (c == nch - 1) ? (fin + (size_t)l * 65536) : (float*)nullptr,
          Tc, c == 0 ? 1 : 0);
    }
  }
  (void)in_sizes; (void)n_in; (void)out_size; (void)ws_size;
}